// Round 3
// baseline (1133.089 us; speedup 1.0000x reference)
//
#include <hip/hip_runtime.h>
#include <math.h>

#define TAU_INV 5.0f   // 1 / 0.2

// ---------------------------------------------------------------------------
// Merged fp32 GEMM: X = [Xu; Xi] (75000 x 256).
//   Q = X @ Wq + bq,  K = X @ Wk + bk   in ONE kernel (A staged once).
// Tile: 64 rows x (128 Q-cols + 128 K-cols), BK=16, A transposed in LDS.
// ---------------------------------------------------------------------------
__global__ __launch_bounds__(256) void gemm_qk_merged(
    const float* __restrict__ Xu, const float* __restrict__ Xi,
    const float* __restrict__ Wq, const float* __restrict__ bq,
    const float* __restrict__ Wk, const float* __restrict__ bk,
    float* __restrict__ Qu, float* __restrict__ Qi,
    float* __restrict__ Ku, float* __restrict__ Ki,
    int U, int I, int D)
{
    __shared__ float As_t[16][68];
    __shared__ float Bs_q[16][132];
    __shared__ float Bs_k[16][132];

    const int tid  = threadIdx.x;
    const int row0 = blockIdx.x * 64;
    const int tr   = tid >> 5;
    const int tc   = tid & 31;

    float4 accq[8], acck[8];
#pragma unroll
    for (int i = 0; i < 8; ++i) {
        accq[i] = make_float4(0.f, 0.f, 0.f, 0.f);
        acck[i] = make_float4(0.f, 0.f, 0.f, 0.f);
    }

    const int ar  = tid >> 2;
    const int akq = (tid & 3) * 4;

    for (int k0 = 0; k0 < D; k0 += 16) {
        {
            int gr = row0 + ar;
            float4 v = make_float4(0.f, 0.f, 0.f, 0.f);
            if (gr < U)            v = *(const float4*)&Xu[(size_t)gr * D + k0 + akq];
            else if (gr - U < I)   v = *(const float4*)&Xi[(size_t)(gr - U) * D + k0 + akq];
            As_t[akq + 0][ar] = v.x;
            As_t[akq + 1][ar] = v.y;
            As_t[akq + 2][ar] = v.z;
            As_t[akq + 3][ar] = v.w;
        }
#pragma unroll
        for (int t = 0; t < 2; ++t) {
            int idx = tid + t * 256;
            int r  = idx >> 5;
            int c4 = (idx & 31) * 4;
            float4 vq = *(const float4*)&Wq[(size_t)(k0 + r) * 128 + c4];
            float4 vk = *(const float4*)&Wk[(size_t)(k0 + r) * 128 + c4];
            *(float4*)&Bs_q[r][c4] = vq;
            *(float4*)&Bs_k[r][c4] = vk;
        }
        __syncthreads();

#pragma unroll
        for (int kk = 0; kk < 16; ++kk) {
            float4 a0  = *(const float4*)&As_t[kk][tr * 8];
            float4 a1  = *(const float4*)&As_t[kk][tr * 8 + 4];
            float4 bqv = *(const float4*)&Bs_q[kk][tc * 4];
            float4 bkv = *(const float4*)&Bs_k[kk][tc * 4];
            float a[8] = {a0.x, a0.y, a0.z, a0.w, a1.x, a1.y, a1.z, a1.w};
#pragma unroll
            for (int i = 0; i < 8; ++i) {
                accq[i].x += a[i] * bqv.x;
                accq[i].y += a[i] * bqv.y;
                accq[i].z += a[i] * bqv.z;
                accq[i].w += a[i] * bqv.w;
                acck[i].x += a[i] * bkv.x;
                acck[i].y += a[i] * bkv.y;
                acck[i].z += a[i] * bkv.z;
                acck[i].w += a[i] * bkv.w;
            }
        }
        __syncthreads();
    }

    const float4 bbq = *(const float4*)&bq[tc * 4];
    const float4 bbk = *(const float4*)&bk[tc * 4];
#pragma unroll
    for (int i = 0; i < 8; ++i) {
        int gr = row0 + tr * 8 + i;
        float4 vq = make_float4(accq[i].x + bbq.x, accq[i].y + bbq.y,
                                accq[i].z + bbq.z, accq[i].w + bbq.w);
        float4 vk = make_float4(acck[i].x + bbk.x, acck[i].y + bbk.y,
                                acck[i].z + bbk.z, acck[i].w + bbk.w);
        if (gr < U) {
            *(float4*)&Qu[(size_t)gr * 128 + tc * 4] = vq;
            *(float4*)&Ku[(size_t)gr * 128 + tc * 4] = vk;
        } else if (gr - U < I) {
            *(float4*)&Qi[(size_t)(gr - U) * 128 + tc * 4] = vq;
            *(float4*)&Ki[(size_t)(gr - U) * 128 + tc * 4] = vk;
        }
    }
}

// ---------------------------------------------------------------------------
// Counting sort of the 2E combined edges by segment.
// Combined segment space: s in [0, U+I): users then items.
//   edge i < E  (ui): seg = ui_rows[i], K-row = U + ui_cols[i], out pos = i
//   edge E + i  (iu): seg = U + ui_cols[i], K-row = ui_rows[i], out pos = E + i
// ---------------------------------------------------------------------------
__global__ void hist_kernel(const int* __restrict__ ui_rows,
                            const int* __restrict__ ui_cols,
                            int* __restrict__ hist, int U, int E)
{
    int i = blockIdx.x * 256 + threadIdx.x;
    if (i < E)          atomicAdd(&hist[ui_rows[i]], 1);
    else if (i < 2 * E) atomicAdd(&hist[U + ui_cols[i - E]], 1);
}

__global__ void scan1(const int* __restrict__ hist, int* __restrict__ offs,
                      int* __restrict__ bsum, int n)
{
    __shared__ int tmp[256];
    int tid = threadIdx.x;
    int i = blockIdx.x * 256 + tid;
    int v = (i < n) ? hist[i] : 0;
    tmp[tid] = v;
    __syncthreads();
    for (int off = 1; off < 256; off <<= 1) {
        int t = (tid >= off) ? tmp[tid - off] : 0;
        __syncthreads();
        tmp[tid] += t;
        __syncthreads();
    }
    if (i < n) offs[i] = tmp[tid] - v;            // exclusive within block
    if (tid == 255) bsum[blockIdx.x] = tmp[255];  // block total
}

__global__ void scan2(int* __restrict__ bsum, int nb)
{
    if (blockIdx.x == 0 && threadIdx.x == 0) {
        int acc = 0;
        for (int i = 0; i < nb; ++i) { int v = bsum[i]; bsum[i] = acc; acc += v; }
    }
}

__global__ void scan3(int* __restrict__ offs, int* __restrict__ cursor,
                      const int* __restrict__ bsum, int n)
{
    int i = blockIdx.x * 256 + threadIdx.x;
    if (i < n) {
        int v = offs[i] + bsum[blockIdx.x];
        offs[i] = v;
        cursor[i] = v;
    }
}

__global__ void scatter_kernel(const int* __restrict__ ui_rows,
                               const int* __restrict__ ui_cols,
                               int* __restrict__ cursor,
                               int* __restrict__ sorted_k,
                               int* __restrict__ sorted_p, int U, int E)
{
    int i = blockIdx.x * 256 + threadIdx.x;
    if (i < E) {
        int s = ui_rows[i];
        int p = atomicAdd(&cursor[s], 1);
        sorted_k[p] = U + ui_cols[i];
        sorted_p[p] = i;
    } else if (i < 2 * E) {
        int ii = i - E;
        int s = U + ui_cols[ii];
        int p = atomicAdd(&cursor[s], 1);
        sorted_k[p] = ui_rows[ii];
        sorted_p[p] = E + ii;
    }
}

// ---------------------------------------------------------------------------
// Fused edge-dot + Gumbel + segment softmax. One wave per segment.
// Q row read once into registers; K rows gathered with a 2-deep pipeline;
// online softmax (M,S) per half-wave, combined across halves; pass 2
// normalizes via z values staged in out[] (final positions).
// ---------------------------------------------------------------------------
__global__ __launch_bounds__(256) void fused_edge_softmax(
    const float* __restrict__ Qall, const float* __restrict__ Kall,
    const int* __restrict__ offs, const int* __restrict__ hist,
    const int* __restrict__ sorted_k, const int* __restrict__ sorted_p,
    const float* __restrict__ noise_ui, const float* __restrict__ noise_iu,
    float* __restrict__ out, int nseg, int E)
{
    const int wid  = (blockIdx.x * 256 + threadIdx.x) >> 6;   // segment id
    const int lane = threadIdx.x & 63;
    if (wid >= nseg) return;
    const int n = hist[wid];
    if (n == 0) return;
    const int base = offs[wid];
    const int half = lane >> 5;   // two edges per wave-iteration
    const int hl   = lane & 31;

    const float4 qv = *(const float4*)&Qall[(size_t)wid * 128 + hl * 4];

    float M = -INFINITY, S = 0.0f;

    // prologue
    int  j     = base + half;
    bool valid = (half < n);
    int  kc    = valid ? sorted_k[j] : sorted_k[base];
    float4 kv  = *(const float4*)&Kall[(size_t)kc * 128 + hl * 4];

    for (int t = 0; t < n; t += 2) {
        // prefetch next pair
        int  jn     = base + t + 2 + half;
        bool validn = (t + 2 + half) < n;
        int  kcn    = validn ? sorted_k[jn] : sorted_k[base];
        float4 kvn  = *(const float4*)&Kall[(size_t)kcn * 128 + hl * 4];
        // process current
        if (valid) {
            float d = qv.x * kv.x + qv.y * kv.y + qv.z * kv.z + qv.w * kv.w;
            d += __shfl_xor(d, 16);
            d += __shfl_xor(d, 8);
            d += __shfl_xor(d, 4);
            d += __shfl_xor(d, 2);
            d += __shfl_xor(d, 1);
            int p = sorted_p[j];
            float nz = (p < E) ? noise_ui[p] : noise_iu[p - E];
            float z = (d - __logf(-__logf(nz))) * TAU_INV;
            if (hl == 0) out[p] = z;          // stage z at final position
            float mn = fmaxf(M, z);
            S = S * __expf(M - mn) + __expf(z - mn);
            M = mn;
        }
        j = jn; valid = validn; kv = kvn;
    }

    // combine the two half-wave states
    {
        float Mo = __shfl_xor(M, 32);
        float So = __shfl_xor(S, 32);
        float Mn = fmaxf(M, Mo);
        S = S * __expf(M - Mn) + So * __expf(Mo - Mn);
        M = Mn;
    }
    const float Sinv = 1.0f / S;

    // pass 2: normalize (z staged in out[]), one edge per lane
    for (int t2 = lane; t2 < n; t2 += 64) {
        int jj = base + t2;
        int p  = sorted_p[jj];
        float z = out[p];
        out[p] = __expf(z - M) * Sinv;
    }
}

// ---------------------------------------------------------------------------
extern "C" void kernel_launch(void* const* d_in, const int* in_sizes, int n_in,
                              void* d_out, int out_size, void* d_ws, size_t ws_size,
                              hipStream_t stream)
{
    const float* user_embed = (const float*)d_in[0];
    const float* item_embed = (const float*)d_in[1];
    const float* Wq = (const float*)d_in[2];
    const float* bq = (const float*)d_in[3];
    const float* Wk = (const float*)d_in[4];
    const float* bk = (const float*)d_in[5];
    const int* ui_rows    = (const int*)d_in[6];
    const int* ui_cols    = (const int*)d_in[7];
    const float* noise_ui = (const float*)d_in[8];
    const float* noise_iu = (const float*)d_in[9];

    const int H = in_sizes[3];           // 128
    const int D = in_sizes[2] / H;       // 256
    const int U = in_sizes[0] / D;       // 50000
    const int I = in_sizes[1] / D;       // 25000
    const int E = in_sizes[6];           // 1600000
    (void)H;

    const int nseg = U + I;

    // ---- workspace layout (floats/ints) ----
    // Qall[(U+I)*128] | Kall[(U+I)*128] | sorted_k[2E] | sorted_p[2E]
    // | hist | offs | cursor | bsum
    float* ws = (float*)d_ws;
    float* Qall = ws;            ws += (size_t)nseg * 128;
    float* Kall = ws;            ws += (size_t)nseg * 128;
    float* Qu = Qall;            float* Qi = Qall + (size_t)U * 128;
    float* Ku = Kall;            float* Ki = Kall + (size_t)U * 128;
    int* sorted_k = (int*)ws;    ws += (size_t)2 * E;
    int* sorted_p = (int*)ws;    ws += (size_t)2 * E;
    int* hist   = (int*)ws;      ws += nseg;
    int* offs   = (int*)ws;      ws += nseg;
    int* cursor = (int*)ws;      ws += nseg;
    int* bsum   = (int*)ws;      ws += ((nseg + 255) / 256) + 1;

    float* out = (float*)d_out;

    hipMemsetAsync(hist, 0, (size_t)nseg * sizeof(int), stream);

    const int gblocks = (U + I + 63) / 64;
    gemm_qk_merged<<<gblocks, 256, 0, stream>>>(user_embed, item_embed,
                                                Wq, bq, Wk, bk,
                                                Qu, Qi, Ku, Ki, U, I, D);

    const int eblocks2 = (2 * E + 255) / 256;
    hist_kernel<<<eblocks2, 256, 0, stream>>>(ui_rows, ui_cols, hist, U, E);

    const int sblocks = (nseg + 255) / 256;
    scan1<<<sblocks, 256, 0, stream>>>(hist, offs, bsum, nseg);
    scan2<<<1, 64, 0, stream>>>(bsum, sblocks);
    scan3<<<sblocks, 256, 0, stream>>>(offs, cursor, bsum, nseg);

    scatter_kernel<<<eblocks2, 256, 0, stream>>>(ui_rows, ui_cols, cursor,
                                                 sorted_k, sorted_p, U, E);

    const int fblocks = (nseg + 3) / 4;   // 4 waves (segments) per 256-thread block
    fused_edge_softmax<<<fblocks, 256, 0, stream>>>(Qall, Kall, offs, hist,
                                                    sorted_k, sorted_p,
                                                    noise_ui, noise_iu,
                                                    out, nseg, E);
}

// Round 4
// 986.379 us; speedup vs baseline: 1.1487x; 1.1487x over previous
//
#include <hip/hip_runtime.h>
#include <math.h>

#define TAU_INV 5.0f   // 1 / 0.2

// ---------------------------------------------------------------------------
// float atomic max via int/uint trick (works for mixed signs, init = -inf)
// ---------------------------------------------------------------------------
__device__ __forceinline__ void atomicMaxFloat(float* addr, float val) {
    if (val >= 0.0f) {
        atomicMax((int*)addr, __float_as_int(val));
    } else {
        atomicMin((unsigned int*)addr, __float_as_uint(val));
    }
}

__global__ void init_seg(float* __restrict__ seg_max, float* __restrict__ seg_sum, int n) {
    int i = blockIdx.x * blockDim.x + threadIdx.x;
    if (i < n) {
        seg_max[i] = -INFINITY;
        seg_sum[i] = 0.0f;
    }
}

// ---------------------------------------------------------------------------
// Tall-skinny GEMM: X = [Xu; Xi] (75000 x 256), W2 = [Wq || Wk] (256 x 256).
// Block = 32 rows x full N=256. A-tile (32 x 256) staged in LDS ONCE
// (k-major, pad 33 -> conflict-free broadcast reads); NO barriers in the
// K-loop; W streamed from global (L2-resident, 256 KB) with a 1-deep
// register pipeline. Thread: rows {r0, r0+8, r0+16, r0+24}, cols c0..c0+7.
// 32 FMA per k per thread -> VALU-bound (floor ~63 us).
// ---------------------------------------------------------------------------
__global__ __launch_bounds__(256) void gemm_qk2(
    const float* __restrict__ Xu, const float* __restrict__ Xi,
    const float* __restrict__ Wq, const float* __restrict__ bq,
    const float* __restrict__ Wk, const float* __restrict__ bk,
    float* __restrict__ Qu, float* __restrict__ Qi,
    float* __restrict__ Ku, float* __restrict__ Ki,
    int U, int I)
{
    __shared__ float As_t[256][33];   // [k][row], 33.8 KB -> 4 blocks/CU

    const int tid  = threadIdx.x;
    const int row0 = blockIdx.x * 32;

    // ---- stage A once: 32 rows x 256 k = 2048 float4, 8 per thread ----
#pragma unroll
    for (int it = 0; it < 8; ++it) {
        int idx = tid + it * 256;        // 0..2047
        int r   = idx >> 6;              // 0..31
        int k4  = (idx & 63) * 4;        // 0..252
        int gr  = row0 + r;
        float4 v = make_float4(0.f, 0.f, 0.f, 0.f);
        if (gr < U)           v = *(const float4*)&Xu[(size_t)gr * 256 + k4];
        else if (gr - U < I)  v = *(const float4*)&Xi[(size_t)(gr - U) * 256 + k4];
        As_t[k4 + 0][r] = v.x;
        As_t[k4 + 1][r] = v.y;
        As_t[k4 + 2][r] = v.z;
        As_t[k4 + 3][r] = v.w;
    }
    __syncthreads();

    const int r0 = tid >> 5;             // 0..7 -> rows r0 + 8i
    const int c0 = (tid & 31) * 8;       // 0..248 (cols in [Q||K])
    const float* Wbase = (c0 < 128) ? (Wq + c0) : (Wk + (c0 - 128));

    float4 acc[4][2];
#pragma unroll
    for (int i = 0; i < 4; ++i) {
        acc[i][0] = make_float4(0.f, 0.f, 0.f, 0.f);
        acc[i][1] = make_float4(0.f, 0.f, 0.f, 0.f);
    }

    float4 w0 = *(const float4*)&Wbase[0];
    float4 w1 = *(const float4*)&Wbase[4];

    for (int k = 0; k < 256; ++k) {
        float4 nw0, nw1;
        if (k < 255) {
            nw0 = *(const float4*)&Wbase[(size_t)(k + 1) * 128 + 0];
            nw1 = *(const float4*)&Wbase[(size_t)(k + 1) * 128 + 4];
        }
        float a0 = As_t[k][r0];
        float a1 = As_t[k][r0 + 8];
        float a2 = As_t[k][r0 + 16];
        float a3 = As_t[k][r0 + 24];
#define FMA_ROW(i, a)                                        \
        acc[i][0].x += (a) * w0.x; acc[i][0].y += (a) * w0.y; \
        acc[i][0].z += (a) * w0.z; acc[i][0].w += (a) * w0.w; \
        acc[i][1].x += (a) * w1.x; acc[i][1].y += (a) * w1.y; \
        acc[i][1].z += (a) * w1.z; acc[i][1].w += (a) * w1.w;
        FMA_ROW(0, a0)
        FMA_ROW(1, a1)
        FMA_ROW(2, a2)
        FMA_ROW(3, a3)
#undef FMA_ROW
        w0 = nw0; w1 = nw1;
    }

    // bias + store
    const float* Bbase = (c0 < 128) ? (bq + c0) : (bk + (c0 - 128));
    float4 bb0 = *(const float4*)&Bbase[0];
    float4 bb1 = *(const float4*)&Bbase[4];
    const int col = (c0 < 128) ? c0 : (c0 - 128);
    float* OU = (c0 < 128) ? Qu : Ku;
    float* OI = (c0 < 128) ? Qi : Ki;

#pragma unroll
    for (int i = 0; i < 4; ++i) {
        int gr = row0 + r0 + 8 * i;
        float4 v0 = make_float4(acc[i][0].x + bb0.x, acc[i][0].y + bb0.y,
                                acc[i][0].z + bb0.z, acc[i][0].w + bb0.w);
        float4 v1 = make_float4(acc[i][1].x + bb1.x, acc[i][1].y + bb1.y,
                                acc[i][1].z + bb1.z, acc[i][1].w + bb1.w);
        if (gr < U) {
            *(float4*)&OU[(size_t)gr * 128 + col]     = v0;
            *(float4*)&OU[(size_t)gr * 128 + col + 4] = v1;
        } else if (gr - U < I) {
            *(float4*)&OI[(size_t)(gr - U) * 128 + col]     = v0;
            *(float4*)&OI[(size_t)(gr - U) * 128 + col + 4] = v1;
        }
    }
}

// ---------------------------------------------------------------------------
// per-edge dot(Q[qidx], K[kidx]) (H=128), z = (w - log(-log(noise))) / tau,
// store z, atomic segment max.  32 lanes per edge, float4 per lane.
// ---------------------------------------------------------------------------
__global__ __launch_bounds__(256) void edge_w(
    const float* __restrict__ Q, const float* __restrict__ K,
    const int* __restrict__ qidx, const int* __restrict__ kidx,
    const float* __restrict__ noise,
    float* __restrict__ z, float* __restrict__ seg_max, int E)
{
    const int gtid = blockIdx.x * 256 + threadIdx.x;
    const int eid  = gtid >> 5;
    const int lane = threadIdx.x & 31;
    if (eid >= E) return;

    const int q = qidx[eid];
    const int k = kidx[eid];
    const float4 qv = *(const float4*)&Q[(size_t)q * 128 + lane * 4];
    const float4 kv = *(const float4*)&K[(size_t)k * 128 + lane * 4];
    float d = qv.x * kv.x + qv.y * kv.y + qv.z * kv.z + qv.w * kv.w;
#pragma unroll
    for (int off = 16; off > 0; off >>= 1)
        d += __shfl_xor(d, off);
    if (lane == 0) {
        float g  = __logf(-__logf(noise[eid]));
        float zz = (d - g) * TAU_INV;
        z[eid] = zz;
        atomicMaxFloat(&seg_max[q], zz);
    }
}

// ---------------------------------------------------------------------------
// sum += exp(z - max[seg])   (z read-only; no extra write stream)
// ---------------------------------------------------------------------------
__global__ void edge_exp(const float* __restrict__ z, const int* __restrict__ seg,
                         const float* __restrict__ seg_max,
                         float* __restrict__ seg_sum, int E)
{
    int i = blockIdx.x * blockDim.x + threadIdx.x;
    if (i >= E) return;
    int s = seg[i];
    atomicAdd(&seg_sum[s], __expf(z[i] - seg_max[s]));
}

// ---------------------------------------------------------------------------
// out = exp(z - max[seg]) / sum[seg]  (in-place on d_out)
// ---------------------------------------------------------------------------
__global__ void edge_norm(float* __restrict__ zv, const int* __restrict__ seg,
                          const float* __restrict__ seg_max,
                          const float* __restrict__ seg_sum, int E)
{
    int i = blockIdx.x * blockDim.x + threadIdx.x;
    if (i >= E) return;
    int s = seg[i];
    zv[i] = __expf(zv[i] - seg_max[s]) / seg_sum[s];
}

// ---------------------------------------------------------------------------
extern "C" void kernel_launch(void* const* d_in, const int* in_sizes, int n_in,
                              void* d_out, int out_size, void* d_ws, size_t ws_size,
                              hipStream_t stream)
{
    const float* user_embed = (const float*)d_in[0];
    const float* item_embed = (const float*)d_in[1];
    const float* Wq = (const float*)d_in[2];
    const float* bq = (const float*)d_in[3];
    const float* Wk = (const float*)d_in[4];
    const float* bk = (const float*)d_in[5];
    const int* ui_rows    = (const int*)d_in[6];
    const int* ui_cols    = (const int*)d_in[7];
    const float* noise_ui = (const float*)d_in[8];
    const float* noise_iu = (const float*)d_in[9];

    const int H = in_sizes[3];           // 128
    const int D = in_sizes[2] / H;       // 256
    const int U = in_sizes[0] / D;       // 50000
    const int I = in_sizes[1] / D;       // 25000
    const int E = in_sizes[6];           // 1600000
    (void)H; (void)D;

    // workspace: Qu | Ku | Qi | Ki | seg_max(U+I) | seg_sum(U+I)   (~77 MB)
    float* ws = (float*)d_ws;
    float* Qu = ws;  ws += (size_t)U * 128;
    float* Ku = ws;  ws += (size_t)U * 128;
    float* Qi = ws;  ws += (size_t)I * 128;
    float* Ki = ws;  ws += (size_t)I * 128;
    float* seg_max = ws; ws += (size_t)(U + I);
    float* seg_sum = ws; ws += (size_t)(U + I);
    float* max_u = seg_max;      float* max_i = seg_max + U;
    float* sum_u = seg_sum;      float* sum_i = seg_sum + U;

    // z lives in d_out across the edge passes
    float* out_ui = (float*)d_out;
    float* out_iu = out_ui + E;

    const int nseg = U + I;
    init_seg<<<(nseg + 255) / 256, 256, 0, stream>>>(seg_max, seg_sum, nseg);

    const int gblocks = (U + I + 31) / 32;
    gemm_qk2<<<gblocks, 256, 0, stream>>>(user_embed, item_embed,
                                          Wq, bq, Wk, bk,
                                          Qu, Qi, Ku, Ki, U, I);

    const int eblocks = (int)(((long long)E * 32 + 255) / 256);
    // ui: Q = Qu[rows], K = Ki[cols], segment = rows (users)
    edge_w<<<eblocks, 256, 0, stream>>>(Qu, Ki, ui_rows, ui_cols, noise_ui, out_ui, max_u, E);
    // iu: Q = Qi[cols], K = Ku[rows], segment = cols (items)
    edge_w<<<eblocks, 256, 0, stream>>>(Qi, Ku, ui_cols, ui_rows, noise_iu, out_iu, max_i, E);

    const int sblocks = (E + 255) / 256;
    edge_exp<<<sblocks, 256, 0, stream>>>(out_ui, ui_rows, max_u, sum_u, E);
    edge_exp<<<sblocks, 256, 0, stream>>>(out_iu, ui_cols, max_i, sum_i, E);

    edge_norm<<<sblocks, 256, 0, stream>>>(out_ui, ui_rows, max_u, sum_u, E);
    edge_norm<<<sblocks, 256, 0, stream>>>(out_iu, ui_cols, max_i, sum_i, E);
}

// Round 5
// 701.047 us; speedup vs baseline: 1.6163x; 1.4070x over previous
//
#include <hip/hip_runtime.h>
#include <hip/hip_fp16.h>
#include <math.h>

#define TAU_INV 5.0f   // 1 / 0.2

// ---------------------------------------------------------------------------
__device__ __forceinline__ void atomicMaxFloat(float* addr, float val) {
    if (val >= 0.0f) {
        atomicMax((int*)addr, __float_as_int(val));
    } else {
        atomicMin((unsigned int*)addr, __float_as_uint(val));
    }
}

__global__ void init_seg(float* __restrict__ seg_max, float* __restrict__ seg_sum, int n) {
    int i = blockIdx.x * blockDim.x + threadIdx.x;
    if (i < n) {
        seg_max[i] = -INFINITY;
        seg_sum[i] = 0.0f;
    }
}

// ---------------------------------------------------------------------------
// Merged fp32 GEMM (R2 structure — known good): X = [Xu; Xi] (75000 x 256).
//   Q = X @ Wq + bq,  K = X @ Wk + bk  in one kernel, A staged once.
// Outputs stored as FP16 (row-major, stride 128) into Qall/Kall
// (rows 0..U-1 = users, U..U+I-1 = items).
// ---------------------------------------------------------------------------
__global__ __launch_bounds__(256) void gemm_qk_merged(
    const float* __restrict__ Xu, const float* __restrict__ Xi,
    const float* __restrict__ Wq, const float* __restrict__ bq,
    const float* __restrict__ Wk, const float* __restrict__ bk,
    __half* __restrict__ Qall, __half* __restrict__ Kall,
    int U, int I, int D)
{
    __shared__ float As_t[16][68];
    __shared__ float Bs_q[16][132];
    __shared__ float Bs_k[16][132];

    const int tid  = threadIdx.x;
    const int row0 = blockIdx.x * 64;
    const int tr   = tid >> 5;
    const int tc   = tid & 31;

    float4 accq[8], acck[8];
#pragma unroll
    for (int i = 0; i < 8; ++i) {
        accq[i] = make_float4(0.f, 0.f, 0.f, 0.f);
        acck[i] = make_float4(0.f, 0.f, 0.f, 0.f);
    }

    const int ar  = tid >> 2;
    const int akq = (tid & 3) * 4;

    for (int k0 = 0; k0 < D; k0 += 16) {
        {
            int gr = row0 + ar;
            float4 v = make_float4(0.f, 0.f, 0.f, 0.f);
            if (gr < U)            v = *(const float4*)&Xu[(size_t)gr * D + k0 + akq];
            else if (gr - U < I)   v = *(const float4*)&Xi[(size_t)(gr - U) * D + k0 + akq];
            As_t[akq + 0][ar] = v.x;
            As_t[akq + 1][ar] = v.y;
            As_t[akq + 2][ar] = v.z;
            As_t[akq + 3][ar] = v.w;
        }
#pragma unroll
        for (int t = 0; t < 2; ++t) {
            int idx = tid + t * 256;
            int r  = idx >> 5;
            int c4 = (idx & 31) * 4;
            float4 vq = *(const float4*)&Wq[(size_t)(k0 + r) * 128 + c4];
            float4 vk = *(const float4*)&Wk[(size_t)(k0 + r) * 128 + c4];
            *(float4*)&Bs_q[r][c4] = vq;
            *(float4*)&Bs_k[r][c4] = vk;
        }
        __syncthreads();

#pragma unroll
        for (int kk = 0; kk < 16; ++kk) {
            float4 a0  = *(const float4*)&As_t[kk][tr * 8];
            float4 a1  = *(const float4*)&As_t[kk][tr * 8 + 4];
            float4 bqv = *(const float4*)&Bs_q[kk][tc * 4];
            float4 bkv = *(const float4*)&Bs_k[kk][tc * 4];
            float a[8] = {a0.x, a0.y, a0.z, a0.w, a1.x, a1.y, a1.z, a1.w};
#pragma unroll
            for (int i = 0; i < 8; ++i) {
                accq[i].x += a[i] * bqv.x;
                accq[i].y += a[i] * bqv.y;
                accq[i].z += a[i] * bqv.z;
                accq[i].w += a[i] * bqv.w;
                acck[i].x += a[i] * bkv.x;
                acck[i].y += a[i] * bkv.y;
                acck[i].z += a[i] * bkv.z;
                acck[i].w += a[i] * bkv.w;
            }
        }
        __syncthreads();
    }

    const float4 bbq = *(const float4*)&bq[tc * 4];
    const float4 bbk = *(const float4*)&bk[tc * 4];
    const int NT = U + I;
#pragma unroll
    for (int i = 0; i < 8; ++i) {
        int gr = row0 + tr * 8 + i;
        if (gr < NT) {
            __half2 q01 = __floats2half2_rn(accq[i].x + bbq.x, accq[i].y + bbq.y);
            __half2 q23 = __floats2half2_rn(accq[i].z + bbq.z, accq[i].w + bbq.w);
            __half2 k01 = __floats2half2_rn(acck[i].x + bbk.x, acck[i].y + bbk.y);
            __half2 k23 = __floats2half2_rn(acck[i].z + bbk.z, acck[i].w + bbk.w);
            uint2 pq, pk;
            pq.x = *(const unsigned int*)&q01;
            pq.y = *(const unsigned int*)&q23;
            pk.x = *(const unsigned int*)&k01;
            pk.y = *(const unsigned int*)&k23;
            *(uint2*)&Qall[(size_t)gr * 128 + tc * 4] = pq;
            *(uint2*)&Kall[(size_t)gr * 128 + tc * 4] = pk;
        }
    }
}

// ---------------------------------------------------------------------------
// per-edge dot over FP16 rows: 16 lanes/edge, 16 B (8 halves) per lane.
// z = (w - log(-log(noise))) * TAU_INV; store z; atomic segment max.
// Row ids: q = qoff + qidx[eid], k = koff + kidx[eid]; segment = qidx[eid].
// ---------------------------------------------------------------------------
__global__ __launch_bounds__(256) void edge_w_h(
    const __half* __restrict__ Q, const __half* __restrict__ K,
    const int* __restrict__ qidx, const int* __restrict__ kidx,
    int qoff, int koff,
    const float* __restrict__ noise,
    float* __restrict__ z, float* __restrict__ seg_max, int E)
{
    const int gtid = blockIdx.x * 256 + threadIdx.x;
    const int eid  = gtid >> 4;
    const int lane = threadIdx.x & 15;
    if (eid >= E) return;

    const int qs = qidx[eid];
    const int qr = qoff + qs;
    const int kr = koff + kidx[eid];

    const uint4 qp = *(const uint4*)(Q + (size_t)qr * 128 + lane * 8);
    const uint4 kp = *(const uint4*)(K + (size_t)kr * 128 + lane * 8);
    const __half2* qh = (const __half2*)&qp;
    const __half2* kh = (const __half2*)&kp;

    float d = 0.0f;
#pragma unroll
    for (int t = 0; t < 4; ++t) {
        float2 a = __half22float2(qh[t]);
        float2 b = __half22float2(kh[t]);
        d += a.x * b.x + a.y * b.y;
    }
    d += __shfl_xor(d, 8);
    d += __shfl_xor(d, 4);
    d += __shfl_xor(d, 2);
    d += __shfl_xor(d, 1);

    if (lane == 0) {
        float g  = __logf(-__logf(noise[eid]));
        float zz = (d - g) * TAU_INV;
        z[eid] = zz;
        atomicMaxFloat(&seg_max[qs], zz);
    }
}

// ---------------------------------------------------------------------------
__global__ void edge_exp(const float* __restrict__ z, const int* __restrict__ seg,
                         const float* __restrict__ seg_max,
                         float* __restrict__ seg_sum, int E)
{
    int i = blockIdx.x * blockDim.x + threadIdx.x;
    if (i >= E) return;
    int s = seg[i];
    atomicAdd(&seg_sum[s], __expf(z[i] - seg_max[s]));
}

__global__ void edge_norm(float* __restrict__ zv, const int* __restrict__ seg,
                          const float* __restrict__ seg_max,
                          const float* __restrict__ seg_sum, int E)
{
    int i = blockIdx.x * blockDim.x + threadIdx.x;
    if (i >= E) return;
    int s = seg[i];
    zv[i] = __expf(zv[i] - seg_max[s]) / seg_sum[s];
}

// ---------------------------------------------------------------------------
extern "C" void kernel_launch(void* const* d_in, const int* in_sizes, int n_in,
                              void* d_out, int out_size, void* d_ws, size_t ws_size,
                              hipStream_t stream)
{
    const float* user_embed = (const float*)d_in[0];
    const float* item_embed = (const float*)d_in[1];
    const float* Wq = (const float*)d_in[2];
    const float* bq = (const float*)d_in[3];
    const float* Wk = (const float*)d_in[4];
    const float* bk = (const float*)d_in[5];
    const int* ui_rows    = (const int*)d_in[6];
    const int* ui_cols    = (const int*)d_in[7];
    const float* noise_ui = (const float*)d_in[8];
    const float* noise_iu = (const float*)d_in[9];

    const int H = in_sizes[3];           // 128
    const int D = in_sizes[2] / H;       // 256
    const int U = in_sizes[0] / D;       // 50000
    const int I = in_sizes[1] / D;       // 25000
    const int E = in_sizes[6];           // 1600000

    const int nseg = U + I;

    // workspace: Qall_h | Kall_h (fp16, rows: users then items) | seg_max | seg_sum
    char* wsc = (char*)d_ws;
    __half* Qall = (__half*)wsc;             wsc += (size_t)nseg * 128 * sizeof(__half);
    __half* Kall = (__half*)wsc;             wsc += (size_t)nseg * 128 * sizeof(__half);
    float* seg_max = (float*)wsc;            wsc += (size_t)nseg * sizeof(float);
    float* seg_sum = (float*)wsc;            wsc += (size_t)nseg * sizeof(float);
    float* max_u = seg_max;      float* max_i = seg_max + U;
    float* sum_u = seg_sum;      float* sum_i = seg_sum + U;

    // z lives in d_out across the edge passes
    float* out_ui = (float*)d_out;
    float* out_iu = out_ui + E;

    init_seg<<<(nseg + 255) / 256, 256, 0, stream>>>(seg_max, seg_sum, nseg);

    const int gblocks = (nseg + 63) / 64;
    gemm_qk_merged<<<gblocks, 256, 0, stream>>>(user_embed, item_embed,
                                                Wq, bq, Wk, bk,
                                                Qall, Kall, U, I, D);

    const int eblocks = (int)(((long long)E * 16 + 255) / 256);
    // ui: Q = Qall[user], K = Kall[U + item], segment = user
    edge_w_h<<<eblocks, 256, 0, stream>>>(Qall, Kall, ui_rows, ui_cols, 0, U,
                                          noise_ui, out_ui, max_u, E);
    // iu: Q = Qall[U + item], K = Kall[user], segment = item
    edge_w_h<<<eblocks, 256, 0, stream>>>(Qall, Kall, ui_cols, ui_rows, U, 0,
                                          noise_iu, out_iu, max_i, E);

    const int sblocks = (E + 255) / 256;
    edge_exp<<<sblocks, 256, 0, stream>>>(out_ui, ui_rows, max_u, sum_u, E);
    edge_exp<<<sblocks, 256, 0, stream>>>(out_iu, ui_cols, max_i, sum_i, E);

    edge_norm<<<sblocks, 256, 0, stream>>>(out_ui, ui_rows, max_u, sum_u, E);
    edge_norm<<<sblocks, 256, 0, stream>>>(out_iu, ui_cols, max_i, sum_i, E);
}